// Round 1
// baseline (175.337 us; speedup 1.0000x reference)
//
#include <hip/hip_runtime.h>
#include <hip/hip_bf16.h>

typedef __attribute__((ext_vector_type(8))) short bf16x8;
typedef __attribute__((ext_vector_type(4))) float f32x4;

__device__ __forceinline__ unsigned short f2bf(float f) {
    unsigned int u = __builtin_bit_cast(unsigned int, f);
    u += 0x7fffu + ((u >> 16) & 1u);   // round-to-nearest-even
    return (unsigned short)(u >> 16);
}

// Swizzled byte offset inside a [128 rows][256 B] LDS tile.
// 16B-unit XOR swizzle: unit' = unit ^ (row & 15). Keeps b128 fragment reads
// conflict-free (8 lanes/slot minimum) and staging writes <= 2-way.
__device__ __forceinline__ int swz(int r, int k /*bf16 col*/) {
    int unit = k >> 3;
    return r * 256 + (((unit ^ (r & 15)) << 4) | ((k & 7) << 1));
}

#define LDS_B_OFF 32768

__global__ __launch_bounds__(256, 2)
void gemm_bf16_batched(const float* __restrict__ A,  // (32, 2048, 128)
                       const float* __restrict__ B,  // (32, 128, 2048)
                       float* __restrict__ C) {      // (32, 2048, 2048)
    __shared__ __align__(16) unsigned char lds[65536];

    const int bid = blockIdx.x;
    const int bh = bid >> 8;          // 0..31
    const int mt = (bid >> 4) & 15;   // M tile
    const int nt = bid & 15;          // N tile

    const float* Ag = A + (size_t)bh * (2048 * 128) + (size_t)mt * (128 * 128);
    const float* Bg = B + (size_t)bh * (128 * 2048) + nt * 128;
    float*       Cg = C + (size_t)bh * (2048 * 2048) + (size_t)(mt * 128) * 2048 + nt * 128;

    const int t = threadIdx.x;

    // ---- stage A tile: 128(m) x 128(k) fp32 -> bf16 LDS [m][k], swizzled ----
#pragma unroll
    for (int i = 0; i < 16; ++i) {
        const int e = i * 1024 + t * 4;
        const int m = e >> 7;
        const int k = e & 127;
        const float4 v = *(const float4*)(Ag + m * 128 + k);
        uint2 w;
        w.x = (unsigned int)f2bf(v.x) | ((unsigned int)f2bf(v.y) << 16);
        w.y = (unsigned int)f2bf(v.z) | ((unsigned int)f2bf(v.w) << 16);
        *(uint2*)(&lds[swz(m, k)]) = w;
    }

    // ---- stage B tile: 128(k) x 128(n) fp32, transpose in-register (4x4)
    //      -> bf16 LDS Bt[n][k], swizzled ----
#pragma unroll
    for (int s = 0; s < 4; ++s) {
        const int k0 = s * 32 + ((t >> 5) << 2);  // 4 consecutive k rows
        const int n0 = (t & 31) << 2;             // 4 consecutive n cols
        const float4 r0 = *(const float4*)(Bg + (size_t)(k0 + 0) * 2048 + n0);
        const float4 r1 = *(const float4*)(Bg + (size_t)(k0 + 1) * 2048 + n0);
        const float4 r2 = *(const float4*)(Bg + (size_t)(k0 + 2) * 2048 + n0);
        const float4 r3 = *(const float4*)(Bg + (size_t)(k0 + 3) * 2048 + n0);
        const float c0[4] = {r0.x, r0.y, r0.z, r0.w};
        const float c1[4] = {r1.x, r1.y, r1.z, r1.w};
        const float c2[4] = {r2.x, r2.y, r2.z, r2.w};
        const float c3[4] = {r3.x, r3.y, r3.z, r3.w};
#pragma unroll
        for (int j = 0; j < 4; ++j) {
            uint2 w;
            w.x = (unsigned int)f2bf(c0[j]) | ((unsigned int)f2bf(c1[j]) << 16);
            w.y = (unsigned int)f2bf(c2[j]) | ((unsigned int)f2bf(c3[j]) << 16);
            *(uint2*)(&lds[LDS_B_OFF + swz(n0 + j, k0)]) = w;
        }
    }

    __syncthreads();

    // ---- MFMA: each wave computes a 64x64 output sub-tile ----
    const int l  = t & 63;
    const int w  = t >> 6;
    const int wm = (w >> 1) * 64;   // wave row offset in 128-tile
    const int wn = (w & 1) * 64;    // wave col offset
    const int lr = l & 15;          // fragment row/col index
    const int lg = l >> 4;          // k-group (0..3)

    f32x4 acc[4][4] = {};

#pragma unroll
    for (int kk = 0; kk < 4; ++kk) {
        const int kbase = kk * 32 + lg * 8;
        bf16x8 a[4], b[4];
#pragma unroll
        for (int mi = 0; mi < 4; ++mi)
            a[mi] = *(const bf16x8*)(&lds[swz(wm + mi * 16 + lr, kbase)]);
#pragma unroll
        for (int ni = 0; ni < 4; ++ni)
            b[ni] = *(const bf16x8*)(&lds[LDS_B_OFF + swz(wn + ni * 16 + lr, kbase)]);
#pragma unroll
        for (int mi = 0; mi < 4; ++mi)
#pragma unroll
            for (int ni = 0; ni < 4; ++ni)
                acc[mi][ni] = __builtin_amdgcn_mfma_f32_16x16x32_bf16(
                    a[mi], b[ni], acc[mi][ni], 0, 0, 0);
    }

    // ---- write C (fp32). D layout: col = lane&15, row = (lane>>4)*4 + j ----
#pragma unroll
    for (int mi = 0; mi < 4; ++mi) {
#pragma unroll
        for (int ni = 0; ni < 4; ++ni) {
            const int row = wm + mi * 16 + lg * 4;
            const int col = wn + ni * 16 + lr;
#pragma unroll
            for (int j = 0; j < 4; ++j) {
                __builtin_nontemporal_store(acc[mi][ni][j],
                                            Cg + (size_t)(row + j) * 2048 + col);
            }
        }
    }
}

extern "C" void kernel_launch(void* const* d_in, const int* in_sizes, int n_in,
                              void* d_out, int out_size, void* d_ws, size_t ws_size,
                              hipStream_t stream) {
    const float* x1 = (const float*)d_in[0];  // (2,16,2048,128)
    const float* x2 = (const float*)d_in[1];  // (2,16,128,2048)
    float* out = (float*)d_out;               // (2,16,2048,2048)
    // 32 batches x 16x16 tiles of 128x128
    gemm_bf16_batched<<<dim3(8192), dim3(256), 0, stream>>>(x1, x2, out);
}